// Round 9
// baseline (2461.772 us; speedup 1.0000x reference)
//
#include <hip/hip_runtime.h>

typedef unsigned int  u32;
typedef unsigned short u16;
typedef unsigned long long u64;
typedef _Float16 half8 __attribute__((ext_vector_type(8)));
typedef short   short8 __attribute__((ext_vector_type(8)));
typedef float   f32x4  __attribute__((ext_vector_type(4)));

#define T_LEN 512
#define BATCH 64
#define EDIM  256
#define HDIM  256
#define G4    1024   // 4*H gate rows

// ---------- numeric helpers ----------
static __device__ __forceinline__ u16 f2bf(float f) {
  u32 u = __builtin_bit_cast(u32, f);
  u = (u + 0x7fffu + ((u >> 16) & 1u)) >> 16;   // RTNE
  return (u16)u;
}
static __device__ __forceinline__ u16 f2h(float a) {
  _Float16 ha = (_Float16)a;
  return __builtin_bit_cast(u16, ha);
}
static __device__ __forceinline__ float h2f(u16 a) {
  return (float)__builtin_bit_cast(_Float16, a);
}
// v_rcp-based: avoids the ~9-instr IEEE div sequence (bench has no fast-math)
static __device__ __forceinline__ float sigf(float x) {
  return __builtin_amdgcn_rcpf(1.0f + __expf(-x));
}
static __device__ __forceinline__ float tanhfast(float x) {
  return fmaf(2.0f, __builtin_amdgcn_rcpf(1.0f + __expf(-2.0f * x)), -1.0f);
}

// ---------- kernel 1: pack W_hh_f into f16 MFMA A-frag order -----------------
// Wf[mt][kt][lane][ji]: flat ((mt*8+kt)*64+lane)*8+ji; value =
// W[mt*16+(lane&15)][kt*32+(lane>>4)*8+ji].
// Also pack kt6-7 frags contiguously per row-block j for imm-offset streaming:
// Wst[(j*8 + (kt-6)*4 + q)*64 + l][8]  (per-lane base + {0..7}*1024 B).
__global__ __launch_bounds__(256) void k_prep(const float* __restrict__ whh,
                                              u16* __restrict__ Wf,
                                              u16* __restrict__ Wst) {
  int cell = blockIdx.x * 256 + threadIdx.x;  // 32768 cells, 8 f16 each
  int mt = cell >> 9, kt = (cell >> 6) & 7, l = cell & 63;
  int gr = mt * 16 + (l & 15);
  int c0 = kt * 32 + (l >> 4) * 8;
  const float4* src = (const float4*)(whh + (size_t)gr * 256 + c0);
  float4 a = src[0], b = src[1];
  u16 o[8] = { f2h(a.x), f2h(a.y), f2h(a.z), f2h(a.w),
               f2h(b.x), f2h(b.y), f2h(b.z), f2h(b.w) };
  *(uint4*)(Wf + (size_t)cell * 8) = *(uint4*)o;
  if (kt >= 6) {
    int q = mt >> 4, jj = mt & 15, s = (kt - 6) * 4 + q;
    *(uint4*)(Wst + ((size_t)(jj * 8 + s) * 64 + l) * 8) = *(uint4*)o;
  }
}

// ---------- kernel 2: xproj via bf16 MFMA, f16 out in k_rnn D-frag order -----
// xp2[t][bg][mt'][lane][r] with mt' = j16*4 + q  (q=gate, j16=row-block).
// (IDENTICAL to the proven round-0 version.)
#define LDSPITCH 264
__global__ __launch_bounds__(256) void k_xproj(const int* __restrict__ x,
                                               const float* __restrict__ emb,
                                               const float* __restrict__ wih,
                                               const float* __restrict__ bih,
                                               const float* __restrict__ bhh,
                                               u16* __restrict__ xp2) {
  __shared__ u16 smA[64 * LDSPITCH];
  __shared__ u16 smB[64 * LDSPITCH];
  const int tn = blockIdx.x, t = blockIdx.y;
  const int tid = threadIdx.x;
  const int r = tid >> 2, q4 = tid & 3;

  { // stage A: emb rows (batch r, timestep t), fp32 -> bf16
    int eidx = x[r * T_LEN + t];
    const float4* src = (const float4*)(emb + (size_t)eidx * EDIM + q4 * 64);
    u16* dst = smA + r * LDSPITCH + q4 * 64;
    #pragma unroll
    for (int i = 0; i < 16; ++i) {
      float4 v = src[i];
      uint2 p;
      p.x = (u32)f2bf(v.x) | ((u32)f2bf(v.y) << 16);
      p.y = (u32)f2bf(v.z) | ((u32)f2bf(v.w) << 16);
      *(uint2*)&dst[i * 4] = p;
    }
  }
  { // stage B: w_ih rows g = tn*64 + r
    const float4* src = (const float4*)(wih + (size_t)(tn * 64 + r) * EDIM + q4 * 64);
    u16* dst = smB + r * LDSPITCH + q4 * 64;
    #pragma unroll
    for (int i = 0; i < 16; ++i) {
      float4 v = src[i];
      uint2 p;
      p.x = (u32)f2bf(v.x) | ((u32)f2bf(v.y) << 16);
      p.y = (u32)f2bf(v.z) | ((u32)f2bf(v.w) << 16);
      *(uint2*)&dst[i * 4] = p;
    }
  }
  __syncthreads();

  const int wv = tid >> 6, lane = tid & 63;
  const int lm = lane & 15, q = lane >> 4;
  f32x4 acc[4];
  #pragma unroll
  for (int nt = 0; nt < 4; ++nt) acc[nt] = (f32x4){0.f, 0.f, 0.f, 0.f};

  const u16* pa = smA + (wv * 16 + lm) * LDSPITCH + q * 8;
  const u16* pb = smB + lm * LDSPITCH + q * 8;
  #pragma unroll
  for (int ks = 0; ks < 8; ++ks) {
    short8 av = *(const short8*)(pa + ks * 32);
    #pragma unroll
    for (int nt = 0; nt < 4; ++nt) {
      short8 bv = *(const short8*)(pb + nt * 16 * LDSPITCH + ks * 32);
      acc[nt] = __builtin_amdgcn_mfma_f32_16x16x32_bf16(av, bv, acc[nt], 0, 0, 0);
    }
  }
  // D: row = batch = wv*16+q*4+rr, col = gate row g = tn*64+nt*16+lm.
  #pragma unroll
  for (int nt = 0; nt < 4; ++nt) {
    int g = tn * 64 + nt * 16 + lm;
    float bias = bih[g] + bhh[g];
    int gq = g >> 8, j16 = (g >> 4) & 15, qdd = (g & 15) >> 2, rb = g & 3;
    int mtp = j16 * 4 + gq;
    #pragma unroll
    for (int rr = 0; rr < 4; ++rr) {
      int bl = q * 4 + rr;   // batch-in-group; bg = wv
      size_t idx = ((((size_t)t * 4 + wv) * 64 + mtp) * 64 + (qdd * 16 + bl)) * 4 + rb;
      xp2[idx] = f2h(acc[nt][rr] + bias);
    }
  }
}

// ---------- kernel 3: recurrence, 4 WGs x 1024 thr, single in-CU barrier -----
// WG bg owns batches [bg*16,+16).  16 waves; wave v owns row-block j = v,
// all 4 gates q; 4 h-elements per lane per step.
// Weights: kt0-3 pinned in AGPRs ("+a": MFMA reads A from AGPR natively);
// kt4-5 LDS (128 KB, wave-private); kt6-7 streamed from Wst (imm offsets).
// KEY register budget (round-8 lesson): 4 waves/SIMD -> 128 unified regs =
// 64 AGPR (weights) + 64 arch VGPR.  Working set must fit 64 arch regs or
// the allocator spills to SCRATCH (r8: WRITE_SIZE 32->1088 KB, dur +50%).
// So: SINGLE x buffer (not dbuf) with END-OF-STEP C-init -- xv is loaded
// early (latency hidden under the MFMA phase) and converted into acc right
// after the gates consume acc (acc regs reused).  Peak arch demand ~58.
// acc C-INITIALIZED from xp (z-add folded into MFMA, free).
// Gate nonlinearities via v_rcp.  Raw `lgkmcnt(0); s_barrier` once per step.
// t=511's xv load reads 128 KB past xp2 (into Wf) -- in-workspace, dead value.
__global__ __launch_bounds__(1024, 4) void k_rnn(const u16* __restrict__ Wf,
                                                 const u16* __restrict__ Wst,
                                                 const u16* __restrict__ xp2,
                                                 u16* __restrict__ hf) {
  extern __shared__ u16 sm[];
  u16* smW = sm;               // 16 waves x 8 frags x 512 u16 = 65536 u16 (128 KB)
  u16* smH = sm + 65536;       // 2 x 4224 u16 (pitch 264) = 16.5 KB
  const int bg = blockIdx.x;
  const int tid = threadIdx.x;
  const int v = tid >> 6, l = tid & 63;
  const int j = v;                    // row-block 0..15
  const int bl = l & 15, qd = l >> 4;

  // ---- kt0-3 resident in AGPRs ----
  half8 Wr[4][4];
  #pragma unroll
  for (int q = 0; q < 4; ++q)
    #pragma unroll
    for (int kt = 0; kt < 4; ++kt)
      Wr[q][kt] = *(const half8*)(Wf + ((size_t)((q * 16 + j) * 8 + kt) * 64 + l) * 8);
  #pragma unroll
  for (int q = 0; q < 4; ++q)
    asm volatile("" : "+a"(Wr[q][0]), "+a"(Wr[q][1]), "+a"(Wr[q][2]), "+a"(Wr[q][3]));

  // ---- kt4-5 staged to LDS (wave-private slots; no cross-wave deps) ----
  #pragma unroll
  for (int q = 0; q < 4; ++q)
    #pragma unroll
    for (int ki = 0; ki < 2; ++ki) {
      uint4 tv = *(const uint4*)(Wf + ((size_t)((q * 16 + j) * 8 + 4 + ki) * 64 + l) * 8);
      *(uint4*)(smW + ((size_t)(v * 8 + q * 2 + ki) * 512 + l * 8)) = tv;
    }

  { // zero h dbuf: 2 x 4224 u16 = 4224 u32
    u32* hz = (u32*)smH;
    for (int i = tid; i < 4224; i += 1024) hz[i] = 0;
  }
  __syncthreads();

  float c[4] = {0.f, 0.f, 0.f, 0.f};

  const u16* xbase = xp2 + (size_t)bg * 16384 + (size_t)j * 1024 + l * 4;  // += 65536/t
  const u16* hrd0 = smH + bl * 264 + qd * 8;
  const int  hwof = bl * 264 + j * 16 + qd * 4;
  const u16* wst_l = Wst + (size_t)j * 4096 + l * 8;   // 8 frags at +s*512 u16

  // prologue: C-init acc for t=0 from xp[0]
  f32x4 acc[4];
  {
    uint2 x0[4];
    #pragma unroll
    for (int q = 0; q < 4; ++q)
      x0[q] = *(const uint2*)(xbase + q * 256);
    #pragma unroll
    for (int q = 0; q < 4; ++q)
      acc[q] = (f32x4){ h2f((u16)x0[q].x), h2f((u16)(x0[q].x >> 16)),
                        h2f((u16)x0[q].y), h2f((u16)(x0[q].y >> 16)) };
  }

  for (int t = 0; t < T_LEN; ++t) {
    u32 zoff = 0;
    asm volatile("" : "+v"(zoff));   // block LICM on the kt6-7 re-stream
    const u16* wp = wst_l + zoff;
    uint4 S6[4];
    #pragma unroll
    for (int q = 0; q < 4; ++q)
      S6[q] = *(const uint4*)(wp + q * 512);
    uint2 xv[4];                     // NEXT step's xp (consumed post-gates)
    #pragma unroll
    for (int q = 0; q < 4; ++q)
      xv[q] = *(const uint2*)(xbase + 65536 + q * 256);

    const u16* hb = hrd0 + (t & 1) * 4224;
    #pragma unroll
    for (int kt = 0; kt < 4; ++kt) {                  // kt0-3: AGPR weights
      half8 Bf = *(const half8*)(hb + kt * 32);
      #pragma unroll
      for (int q = 0; q < 4; ++q)
        acc[q] = __builtin_amdgcn_mfma_f32_16x16x32_f16(Wr[q][kt], Bf, acc[q], 0, 0, 0);
    }
    #pragma unroll
    for (int kt = 4; kt < 6; ++kt) {                  // kt4-5: LDS weights
      half8 Bf = *(const half8*)(hb + kt * 32);
      #pragma unroll
      for (int q = 0; q < 4; ++q) {
        half8 Af = *(const half8*)(smW + ((size_t)(v * 8 + q * 2 + (kt - 4)) * 512 + l * 8));
        acc[q] = __builtin_amdgcn_mfma_f32_16x16x32_f16(Af, Bf, acc[q], 0, 0, 0);
      }
    }
    {
      half8 Bf = *(const half8*)(hb + 6 * 32);        // kt6: S6 (dies here)
      #pragma unroll
      for (int q = 0; q < 4; ++q)
        acc[q] = __builtin_amdgcn_mfma_f32_16x16x32_f16(
            __builtin_bit_cast(half8, S6[q]), Bf, acc[q], 0, 0, 0);
    }
    uint4 S7[4];                                      // S7 after kt6 (S6 dead)
    #pragma unroll
    for (int q = 0; q < 4; ++q)
      S7[q] = *(const uint4*)(wp + 2048 + q * 512);
    {
      half8 Bf = *(const half8*)(hb + 7 * 32);        // kt7: S7
      #pragma unroll
      for (int q = 0; q < 4; ++q)
        acc[q] = __builtin_amdgcn_mfma_f32_16x16x32_f16(
            __builtin_bit_cast(half8, S7[q]), Bf, acc[q], 0, 0, 0);
    }

    // gates for rows j*16 + qd*4 + r, batch bg*16 + bl  (z = acc, C-init'd)
    float hn[4];
    #pragma unroll
    for (int r = 0; r < 4; ++r) {
      float zi = acc[0][r], zf = acc[1][r], zg = acc[2][r], zo = acc[3][r];
      c[r] = sigf(zf) * c[r] + sigf(zi) * tanhfast(zg);
      hn[r] = sigf(zo) * tanhfast(c[r]);
    }
    u32 lo = __builtin_bit_cast(u32, __builtin_amdgcn_cvt_pkrtz(hn[0], hn[1]));
    u32 hi = __builtin_bit_cast(u32, __builtin_amdgcn_cvt_pkrtz(hn[2], hn[3]));
    if (t == T_LEN - 1) {
      *(uint2*)(hf + (size_t)(bg * 16 + bl) * 256 + j * 16 + qd * 4) = make_uint2(lo, hi);
    } else {
      *(uint2*)(smH + ((t + 1) & 1) * 4224 + hwof) = make_uint2(lo, hi);
    }

    // C-init next step's acc from xv (acc regs dead after gates -> reused;
    // t=511's init is dead but harmless)
    #pragma unroll
    for (int q = 0; q < 4; ++q)
      acc[q] = (f32x4){ h2f((u16)xv[q].x), h2f((u16)(xv[q].x >> 16)),
                        h2f((u16)xv[q].y), h2f((u16)(xv[q].y >> 16)) };

    xbase += 65536;
    asm volatile("s_waitcnt lgkmcnt(0)\n\ts_barrier" ::: "memory");
  }
}

// ---------- kernel 4: backward single step + fc1 + fc2 ----------
__global__ __launch_bounds__(256) void k_tail(const int* __restrict__ x,
                                              const float* __restrict__ emb,
                                              const float* __restrict__ wihb,
                                              const float* __restrict__ bihb,
                                              const float* __restrict__ bhhb,
                                              const float* __restrict__ fc1w,
                                              const float* __restrict__ fc1b,
                                              const float* __restrict__ fc2w,
                                              const float* __restrict__ fc2b,
                                              const u16* __restrict__ hf,
                                              float* __restrict__ out) {
  const int b = blockIdx.x, tid = threadIdx.x;
  __shared__ float e[EDIM], hb[HDIM], hfl[HDIM], f1[24];
  e[tid]   = emb[(size_t)x[b * T_LEN + (T_LEN - 1)] * EDIM + tid];
  hfl[tid] = h2f(hf[b * HDIM + tid]);
  __syncthreads();

  float z[4];
  #pragma unroll
  for (int gq = 0; gq < 4; ++gq) {
    int g = gq * HDIM + tid;
    float s = bihb[g] + bhhb[g];
    const float4* wr = (const float4*)(wihb + (size_t)g * EDIM);
    #pragma unroll 8
    for (int k = 0; k < 64; ++k) {
      float4 w = wr[k];
      s += w.x * e[4 * k] + w.y * e[4 * k + 1] + w.z * e[4 * k + 2] + w.w * e[4 * k + 3];
    }
    z[gq] = s;
  }
  float cb = sigf(z[0]) * tanhfast(z[2]);   // c0 = 0
  hb[tid] = sigf(z[3]) * tanhfast(cb);
  __syncthreads();

  if (tid < 24) {
    float s = fc1b[tid];
    const float* w = fc1w + tid * 512;
    #pragma unroll 8
    for (int k = 0; k < HDIM; ++k) s += w[k] * hfl[k] + w[HDIM + k] * hb[k];
    f1[tid] = fmaxf(s, 0.f);
  }
  __syncthreads();
  if (tid < 2) {
    float s = fc2b[tid];
    #pragma unroll
    for (int k = 0; k < 24; ++k) s += fc2w[tid * 24 + k] * f1[k];
    out[b * 2 + tid] = s;
  }
}

// ---------- launch ----------
extern "C" void kernel_launch(void* const* d_in, const int* in_sizes, int n_in,
                              void* d_out, int out_size, void* d_ws, size_t ws_size,
                              hipStream_t stream) {
  const int*   x     = (const int*)  d_in[0];
  const float* emb   = (const float*)d_in[1];
  const float* wih_f = (const float*)d_in[2];
  const float* whh_f = (const float*)d_in[3];
  const float* bih_f = (const float*)d_in[4];
  const float* bhh_f = (const float*)d_in[5];
  const float* wih_b = (const float*)d_in[6];
  // d_in[7] = w_hh_b: unused (backward runs exactly one step from zero state)
  const float* bih_b = (const float*)d_in[8];
  const float* bhh_b = (const float*)d_in[9];
  const float* fc1w  = (const float*)d_in[10];
  const float* fc1b  = (const float*)d_in[11];
  const float* fc2w  = (const float*)d_in[12];
  const float* fc2b  = (const float*)d_in[13];
  float* out = (float*)d_out;

  // workspace: xp2 64 MiB | Wf 512 KiB | Wst 128 KiB | hf16 32 KiB
  char* ws = (char*)d_ws;
  u16* xp2  = (u16*)ws;
  u16* Wf   = (u16*)(ws + 67108864);
  u16* Wst  = (u16*)(ws + 67108864 + 524288);
  u16* hf16 = (u16*)(ws + 67108864 + 524288 + 131072);

  k_prep <<<128, 256, 0, stream>>>(whh_f, Wf, Wst);
  k_xproj<<<dim3(16, 512), 256, 0, stream>>>(x, emb, wih_f, bih_f, bhh_f, xp2);
  k_rnn  <<<4, 1024, 147968, stream>>>(Wf, Wst, xp2, hf16);
  k_tail <<<BATCH, 256, 0, stream>>>(x, emb, wih_b, bih_b, bhh_b,
                                     fc1w, fc1b, fc2w, fc2b, hf16, out);
}

// Round 10
// 2432.471 us; speedup vs baseline: 1.0120x; 1.0120x over previous
//
#include <hip/hip_runtime.h>

typedef unsigned int  u32;
typedef unsigned short u16;
typedef unsigned long long u64;
typedef _Float16 half8 __attribute__((ext_vector_type(8)));
typedef short   short8 __attribute__((ext_vector_type(8)));
typedef float   f32x4  __attribute__((ext_vector_type(4)));

#define T_LEN 512
#define BATCH 64
#define EDIM  256
#define HDIM  256
#define G4    1024   // 4*H gate rows

// ---------- numeric helpers ----------
static __device__ __forceinline__ u16 f2bf(float f) {
  u32 u = __builtin_bit_cast(u32, f);
  u = (u + 0x7fffu + ((u >> 16) & 1u)) >> 16;   // RTNE
  return (u16)u;
}
static __device__ __forceinline__ u16 f2h(float a) {
  _Float16 ha = (_Float16)a;
  return __builtin_bit_cast(u16, ha);
}
static __device__ __forceinline__ float h2f(u16 a) {
  return (float)__builtin_bit_cast(_Float16, a);
}
// v_rcp-based: avoids the ~9-instr IEEE div sequence (bench has no fast-math)
static __device__ __forceinline__ float sigf(float x) {
  return __builtin_amdgcn_rcpf(1.0f + __expf(-x));
}
static __device__ __forceinline__ float tanhfast(float x) {
  return fmaf(2.0f, __builtin_amdgcn_rcpf(1.0f + __expf(-2.0f * x)), -1.0f);
}

// ---------- kernel 1: pack W_hh_f into f16 MFMA A-frag order -----------------
// Wf[mt][kt][lane][ji]: flat ((mt*8+kt)*64+lane)*8+ji; value =
// W[mt*16+(lane&15)][kt*32+(lane>>4)*8+ji].
// Also pack kt6-7 frags contiguously per row-block j for imm-offset streaming:
// Wst[(j*8 + (kt-6)*4 + q)*64 + l][8]  (per-lane base + {0..7}*1024 B).
__global__ __launch_bounds__(256) void k_prep(const float* __restrict__ whh,
                                              u16* __restrict__ Wf,
                                              u16* __restrict__ Wst) {
  int cell = blockIdx.x * 256 + threadIdx.x;  // 32768 cells, 8 f16 each
  int mt = cell >> 9, kt = (cell >> 6) & 7, l = cell & 63;
  int gr = mt * 16 + (l & 15);
  int c0 = kt * 32 + (l >> 4) * 8;
  const float4* src = (const float4*)(whh + (size_t)gr * 256 + c0);
  float4 a = src[0], b = src[1];
  u16 o[8] = { f2h(a.x), f2h(a.y), f2h(a.z), f2h(a.w),
               f2h(b.x), f2h(b.y), f2h(b.z), f2h(b.w) };
  *(uint4*)(Wf + (size_t)cell * 8) = *(uint4*)o;
  if (kt >= 6) {
    int q = mt >> 4, jj = mt & 15, s = (kt - 6) * 4 + q;
    *(uint4*)(Wst + ((size_t)(jj * 8 + s) * 64 + l) * 8) = *(uint4*)o;
  }
}

// ---------- kernel 2: xproj via bf16 MFMA, f16 out in k_rnn D-frag order -----
// xp2[t][bg][mt'][lane][r] with mt' = j16*4 + q  (q=gate, j16=row-block).
// (IDENTICAL to the proven round-0 version.)
#define LDSPITCH 264
__global__ __launch_bounds__(256) void k_xproj(const int* __restrict__ x,
                                               const float* __restrict__ emb,
                                               const float* __restrict__ wih,
                                               const float* __restrict__ bih,
                                               const float* __restrict__ bhh,
                                               u16* __restrict__ xp2) {
  __shared__ u16 smA[64 * LDSPITCH];
  __shared__ u16 smB[64 * LDSPITCH];
  const int tn = blockIdx.x, t = blockIdx.y;
  const int tid = threadIdx.x;
  const int r = tid >> 2, q4 = tid & 3;

  { // stage A: emb rows (batch r, timestep t), fp32 -> bf16
    int eidx = x[r * T_LEN + t];
    const float4* src = (const float4*)(emb + (size_t)eidx * EDIM + q4 * 64);
    u16* dst = smA + r * LDSPITCH + q4 * 64;
    #pragma unroll
    for (int i = 0; i < 16; ++i) {
      float4 v = src[i];
      uint2 p;
      p.x = (u32)f2bf(v.x) | ((u32)f2bf(v.y) << 16);
      p.y = (u32)f2bf(v.z) | ((u32)f2bf(v.w) << 16);
      *(uint2*)&dst[i * 4] = p;
    }
  }
  { // stage B: w_ih rows g = tn*64 + r
    const float4* src = (const float4*)(wih + (size_t)(tn * 64 + r) * EDIM + q4 * 64);
    u16* dst = smB + r * LDSPITCH + q4 * 64;
    #pragma unroll
    for (int i = 0; i < 16; ++i) {
      float4 v = src[i];
      uint2 p;
      p.x = (u32)f2bf(v.x) | ((u32)f2bf(v.y) << 16);
      p.y = (u32)f2bf(v.z) | ((u32)f2bf(v.w) << 16);
      *(uint2*)&dst[i * 4] = p;
    }
  }
  __syncthreads();

  const int wv = tid >> 6, lane = tid & 63;
  const int lm = lane & 15, q = lane >> 4;
  f32x4 acc[4];
  #pragma unroll
  for (int nt = 0; nt < 4; ++nt) acc[nt] = (f32x4){0.f, 0.f, 0.f, 0.f};

  const u16* pa = smA + (wv * 16 + lm) * LDSPITCH + q * 8;
  const u16* pb = smB + lm * LDSPITCH + q * 8;
  #pragma unroll
  for (int ks = 0; ks < 8; ++ks) {
    short8 av = *(const short8*)(pa + ks * 32);
    #pragma unroll
    for (int nt = 0; nt < 4; ++nt) {
      short8 bv = *(const short8*)(pb + nt * 16 * LDSPITCH + ks * 32);
      acc[nt] = __builtin_amdgcn_mfma_f32_16x16x32_bf16(av, bv, acc[nt], 0, 0, 0);
    }
  }
  // D: row = batch = wv*16+q*4+rr, col = gate row g = tn*64+nt*16+lm.
  #pragma unroll
  for (int nt = 0; nt < 4; ++nt) {
    int g = tn * 64 + nt * 16 + lm;
    float bias = bih[g] + bhh[g];
    int gq = g >> 8, j16 = (g >> 4) & 15, qdd = (g & 15) >> 2, rb = g & 3;
    int mtp = j16 * 4 + gq;
    #pragma unroll
    for (int rr = 0; rr < 4; ++rr) {
      int bl = q * 4 + rr;   // batch-in-group; bg = wv
      size_t idx = ((((size_t)t * 4 + wv) * 64 + mtp) * 64 + (qdd * 16 + bl)) * 4 + rb;
      xp2[idx] = f2h(acc[nt][rr] + bias);
    }
  }
}

// ---------- kernel 3: recurrence, 4 WGs x 1024 thr, single in-CU barrier -----
// WG bg owns batches [bg*16,+16).  16 waves; wave v owns row-block j = v,
// all 4 gates q; 4 h-elements per lane per step.
// Weights: kt0-3 pinned in AGPRs ("+a": MFMA A reads AGPR natively); kt4-5
// LDS (128 KB wave-private); kt6-7 streamed from Wst (imm offsets, laundered).
// REGISTER DISCIPLINE (r8/r9 lesson): 4 waves/SIMD -> 64 AGPR (weights) +
// 64 arch VGPR.  The scheduler must be FENCED (sched_barrier(0)) so S6 and
// S7 are never live together: fence -> kt6 (S6 dies) -> fence -> S7 loads ->
// kt7.  Peak arch ~56.  Without fences the scheduler clusters all loads at
// the step top (~70+ live) and spills to scratch (r8: WRITE 1088 KB; r9: 576).
// acc C-INITIALIZED from xp (z-add folded into MFMA); xv prefetched at step
// top, converted into acc after the gates consume it (acc regs reused).
// Final iteration PEELED (loop body branch-free, static parity).
// Gate nonlinearities via v_rcp.  Raw `lgkmcnt(0); s_barrier` once per step,
// followed by sched_barrier(0) (rule #18).
__global__ __launch_bounds__(1024, 4) void k_rnn(const u16* __restrict__ Wf,
                                                 const u16* __restrict__ Wst,
                                                 const u16* __restrict__ xp2,
                                                 u16* __restrict__ hf) {
  extern __shared__ u16 sm[];
  u16* smW = sm;               // 16 waves x 8 frags x 512 u16 = 65536 u16 (128 KB)
  u16* smH = sm + 65536;       // 2 x 4224 u16 (pitch 264) = 16.5 KB
  const int bg = blockIdx.x;
  const int tid = threadIdx.x;
  const int v = tid >> 6, l = tid & 63;
  const int j = v;                    // row-block 0..15
  const int bl = l & 15, qd = l >> 4;

  // ---- kt0-3 resident in AGPRs ----
  half8 Wr[4][4];
  #pragma unroll
  for (int q = 0; q < 4; ++q)
    #pragma unroll
    for (int kt = 0; kt < 4; ++kt)
      Wr[q][kt] = *(const half8*)(Wf + ((size_t)((q * 16 + j) * 8 + kt) * 64 + l) * 8);
  #pragma unroll
  for (int q = 0; q < 4; ++q)
    asm volatile("" : "+a"(Wr[q][0]), "+a"(Wr[q][1]), "+a"(Wr[q][2]), "+a"(Wr[q][3]));

  // ---- kt4-5 staged to LDS (wave-private slots; no cross-wave deps) ----
  #pragma unroll
  for (int q = 0; q < 4; ++q)
    #pragma unroll
    for (int ki = 0; ki < 2; ++ki) {
      uint4 tv = *(const uint4*)(Wf + ((size_t)((q * 16 + j) * 8 + 4 + ki) * 64 + l) * 8);
      *(uint4*)(smW + ((size_t)(v * 8 + q * 2 + ki) * 512 + l * 8)) = tv;
    }

  { // zero h dbuf: 2 x 4224 u16 = 4224 u32
    u32* hz = (u32*)smH;
    for (int i = tid; i < 4224; i += 1024) hz[i] = 0;
  }
  __syncthreads();

  float c[4] = {0.f, 0.f, 0.f, 0.f};

  const u16* xbase = xp2 + (size_t)bg * 16384 + (size_t)j * 1024 + l * 4;  // += 65536/t
  const u16* hrd0 = smH + bl * 264 + qd * 8;
  const int  hwof = bl * 264 + j * 16 + qd * 4;
  const u16* wst_l = Wst + (size_t)j * 4096 + l * 8;   // 8 frags at +s*512 u16

  // prologue: C-init acc for t=0 from xp[0]
  f32x4 acc[4];
  {
    uint2 x0[4];
    #pragma unroll
    for (int q = 0; q < 4; ++q)
      x0[q] = *(const uint2*)(xbase + q * 256);
    #pragma unroll
    for (int q = 0; q < 4; ++q)
      acc[q] = (f32x4){ h2f((u16)x0[q].x), h2f((u16)(x0[q].x >> 16)),
                        h2f((u16)x0[q].y), h2f((u16)(x0[q].y >> 16)) };
  }

#define STEP(PAR) do {                                                         \
    u32 zoff = 0;                                                              \
    asm volatile("" : "+v"(zoff));   /* block LICM on the kt6-7 re-stream */   \
    const u16* wp = wst_l + zoff;                                              \
    uint4 S6[4];                                                               \
    _Pragma("unroll")                                                          \
    for (int q = 0; q < 4; ++q) S6[q] = *(const uint4*)(wp + q * 512);         \
    uint2 xv[4];                     /* next step's xp: consumed at C-init */  \
    _Pragma("unroll")                                                          \
    for (int q = 0; q < 4; ++q)                                                \
      xv[q] = *(const uint2*)(xbase + 65536 + q * 256);                        \
    const u16* hb = hrd0 + (PAR) * 4224;                                       \
    _Pragma("unroll")                                                          \
    for (int kt = 0; kt < 4; ++kt) {                /* kt0-3: AGPR weights */  \
      half8 Bf = *(const half8*)(hb + kt * 32);                                \
      _Pragma("unroll")                                                        \
      for (int q = 0; q < 4; ++q)                                              \
        acc[q] = __builtin_amdgcn_mfma_f32_16x16x32_f16(Wr[q][kt], Bf,         \
                                                        acc[q], 0, 0, 0);      \
    }                                                                          \
    _Pragma("unroll")                                                          \
    for (int kt = 4; kt < 6; ++kt) {                /* kt4-5: LDS weights */   \
      half8 Bf = *(const half8*)(hb + kt * 32);                                \
      _Pragma("unroll")                                                        \
      for (int q = 0; q < 4; ++q) {                                            \
        half8 Af = *(const half8*)(smW +                                       \
                     ((size_t)(v * 8 + q * 2 + (kt - 4)) * 512 + l * 8));      \
        acc[q] = __builtin_amdgcn_mfma_f32_16x16x32_f16(Af, Bf,                \
                                                        acc[q], 0, 0, 0);      \
      }                                                                        \
    }                                                                          \
    __builtin_amdgcn_sched_barrier(0);              /* S6 consumed NOW */      \
    {                                                                          \
      half8 Bf = *(const half8*)(hb + 6 * 32);      /* kt6: S6 dies here */    \
      _Pragma("unroll")                                                        \
      for (int q = 0; q < 4; ++q)                                              \
        acc[q] = __builtin_amdgcn_mfma_f32_16x16x32_f16(                       \
            __builtin_bit_cast(half8, S6[q]), Bf, acc[q], 0, 0, 0);            \
    }                                                                          \
    __builtin_amdgcn_sched_barrier(0);              /* S7 cannot hoist */      \
    uint4 S7[4];                                                               \
    _Pragma("unroll")                                                          \
    for (int q = 0; q < 4; ++q)                                                \
      S7[q] = *(const uint4*)(wp + 2048 + q * 512);                            \
    {                                                                          \
      half8 Bf = *(const half8*)(hb + 7 * 32);      /* kt7: S7 */              \
      _Pragma("unroll")                                                        \
      for (int q = 0; q < 4; ++q)                                              \
        acc[q] = __builtin_amdgcn_mfma_f32_16x16x32_f16(                       \
            __builtin_bit_cast(half8, S7[q]), Bf, acc[q], 0, 0, 0);            \
    }                                                                          \
    float hn[4];                     /* gates: z = acc directly (C-init) */    \
    _Pragma("unroll")                                                          \
    for (int r = 0; r < 4; ++r) {                                              \
      float zi = acc[0][r], zf = acc[1][r], zg = acc[2][r], zo = acc[3][r];    \
      c[r] = sigf(zf) * c[r] + sigf(zi) * tanhfast(zg);                        \
      hn[r] = sigf(zo) * tanhfast(c[r]);                                       \
    }                                                                          \
    u32 lo = __builtin_bit_cast(u32, __builtin_amdgcn_cvt_pkrtz(hn[0], hn[1]));\
    u32 hi = __builtin_bit_cast(u32, __builtin_amdgcn_cvt_pkrtz(hn[2], hn[3]));\
    *(uint2*)(smH + (1 - (PAR)) * 4224 + hwof) = make_uint2(lo, hi);           \
    _Pragma("unroll")                /* C-init next acc (regs reused) */       \
    for (int q = 0; q < 4; ++q)                                                \
      acc[q] = (f32x4){ h2f((u16)xv[q].x), h2f((u16)(xv[q].x >> 16)),          \
                        h2f((u16)xv[q].y), h2f((u16)(xv[q].y >> 16)) };        \
    xbase += 65536;                                                            \
    asm volatile("s_waitcnt lgkmcnt(0)\n\ts_barrier" ::: "memory");            \
    __builtin_amdgcn_sched_barrier(0);              /* rule #18 fence */       \
  } while (0)

  for (int tt = 0; tt < 255; ++tt) {   // steps 0..509
    STEP(0);
    STEP(1);
  }
  STEP(0);                             // step 510 (C-inits acc from xp[511])

  { // final step t=511: no prefetch, no smH write, output to hf, no barrier
    u32 zoff = 0;
    asm volatile("" : "+v"(zoff));
    const u16* wp = wst_l + zoff;
    uint4 S6[4];
    #pragma unroll
    for (int q = 0; q < 4; ++q) S6[q] = *(const uint4*)(wp + q * 512);
    const u16* hb = hrd0 + 4224;       // parity 1
    #pragma unroll
    for (int kt = 0; kt < 4; ++kt) {
      half8 Bf = *(const half8*)(hb + kt * 32);
      #pragma unroll
      for (int q = 0; q < 4; ++q)
        acc[q] = __builtin_amdgcn_mfma_f32_16x16x32_f16(Wr[q][kt], Bf, acc[q], 0, 0, 0);
    }
    #pragma unroll
    for (int kt = 4; kt < 6; ++kt) {
      half8 Bf = *(const half8*)(hb + kt * 32);
      #pragma unroll
      for (int q = 0; q < 4; ++q) {
        half8 Af = *(const half8*)(smW + ((size_t)(v * 8 + q * 2 + (kt - 4)) * 512 + l * 8));
        acc[q] = __builtin_amdgcn_mfma_f32_16x16x32_f16(Af, Bf, acc[q], 0, 0, 0);
      }
    }
    {
      half8 Bf = *(const half8*)(hb + 6 * 32);
      #pragma unroll
      for (int q = 0; q < 4; ++q)
        acc[q] = __builtin_amdgcn_mfma_f32_16x16x32_f16(
            __builtin_bit_cast(half8, S6[q]), Bf, acc[q], 0, 0, 0);
    }
    uint4 S7[4];
    #pragma unroll
    for (int q = 0; q < 4; ++q)
      S7[q] = *(const uint4*)(wp + 2048 + q * 512);
    {
      half8 Bf = *(const half8*)(hb + 7 * 32);
      #pragma unroll
      for (int q = 0; q < 4; ++q)
        acc[q] = __builtin_amdgcn_mfma_f32_16x16x32_f16(
            __builtin_bit_cast(half8, S7[q]), Bf, acc[q], 0, 0, 0);
    }
    float hn[4];
    #pragma unroll
    for (int r = 0; r < 4; ++r) {
      float zi = acc[0][r], zf = acc[1][r], zg = acc[2][r], zo = acc[3][r];
      c[r] = sigf(zf) * c[r] + sigf(zi) * tanhfast(zg);
      hn[r] = sigf(zo) * tanhfast(c[r]);
    }
    u32 lo = __builtin_bit_cast(u32, __builtin_amdgcn_cvt_pkrtz(hn[0], hn[1]));
    u32 hi = __builtin_bit_cast(u32, __builtin_amdgcn_cvt_pkrtz(hn[2], hn[3]));
    *(uint2*)(hf + (size_t)(bg * 16 + bl) * 256 + j * 16 + qd * 4) = make_uint2(lo, hi);
  }
#undef STEP
}

// ---------- kernel 4: backward single step + fc1 + fc2 ----------
__global__ __launch_bounds__(256) void k_tail(const int* __restrict__ x,
                                              const float* __restrict__ emb,
                                              const float* __restrict__ wihb,
                                              const float* __restrict__ bihb,
                                              const float* __restrict__ bhhb,
                                              const float* __restrict__ fc1w,
                                              const float* __restrict__ fc1b,
                                              const float* __restrict__ fc2w,
                                              const float* __restrict__ fc2b,
                                              const u16* __restrict__ hf,
                                              float* __restrict__ out) {
  const int b = blockIdx.x, tid = threadIdx.x;
  __shared__ float e[EDIM], hb[HDIM], hfl[HDIM], f1[24];
  e[tid]   = emb[(size_t)x[b * T_LEN + (T_LEN - 1)] * EDIM + tid];
  hfl[tid] = h2f(hf[b * HDIM + tid]);
  __syncthreads();

  float z[4];
  #pragma unroll
  for (int gq = 0; gq < 4; ++gq) {
    int g = gq * HDIM + tid;
    float s = bihb[g] + bhhb[g];
    const float4* wr = (const float4*)(wihb + (size_t)g * EDIM);
    #pragma unroll 8
    for (int k = 0; k < 64; ++k) {
      float4 w = wr[k];
      s += w.x * e[4 * k] + w.y * e[4 * k + 1] + w.z * e[4 * k + 2] + w.w * e[4 * k + 3];
    }
    z[gq] = s;
  }
  float cb = sigf(z[0]) * tanhfast(z[2]);   // c0 = 0
  hb[tid] = sigf(z[3]) * tanhfast(cb);
  __syncthreads();

  if (tid < 24) {
    float s = fc1b[tid];
    const float* w = fc1w + tid * 512;
    #pragma unroll 8
    for (int k = 0; k < HDIM; ++k) s += w[k] * hfl[k] + w[HDIM + k] * hb[k];
    f1[tid] = fmaxf(s, 0.f);
  }
  __syncthreads();
  if (tid < 2) {
    float s = fc2b[tid];
    #pragma unroll
    for (int k = 0; k < 24; ++k) s += fc2w[tid * 24 + k] * f1[k];
    out[b * 2 + tid] = s;
  }
}

// ---------- launch ----------
extern "C" void kernel_launch(void* const* d_in, const int* in_sizes, int n_in,
                              void* d_out, int out_size, void* d_ws, size_t ws_size,
                              hipStream_t stream) {
  const int*   x     = (const int*)  d_in[0];
  const float* emb   = (const float*)d_in[1];
  const float* wih_f = (const float*)d_in[2];
  const float* whh_f = (const float*)d_in[3];
  const float* bih_f = (const float*)d_in[4];
  const float* bhh_f = (const float*)d_in[5];
  const float* wih_b = (const float*)d_in[6];
  // d_in[7] = w_hh_b: unused (backward runs exactly one step from zero state)
  const float* bih_b = (const float*)d_in[8];
  const float* bhh_b = (const float*)d_in[9];
  const float* fc1w  = (const float*)d_in[10];
  const float* fc1b  = (const float*)d_in[11];
  const float* fc2w  = (const float*)d_in[12];
  const float* fc2b  = (const float*)d_in[13];
  float* out = (float*)d_out;

  // workspace: xp2 64 MiB | Wf 512 KiB | Wst 128 KiB | hf16 32 KiB
  char* ws = (char*)d_ws;
  u16* xp2  = (u16*)ws;
  u16* Wf   = (u16*)(ws + 67108864);
  u16* Wst  = (u16*)(ws + 67108864 + 524288);
  u16* hf16 = (u16*)(ws + 67108864 + 524288 + 131072);

  k_prep <<<128, 256, 0, stream>>>(whh_f, Wf, Wst);
  k_xproj<<<dim3(16, 512), 256, 0, stream>>>(x, emb, wih_f, bih_f, bhh_f, xp2);
  k_rnn  <<<4, 1024, 147968, stream>>>(Wf, Wst, xp2, hf16);
  k_tail <<<BATCH, 256, 0, stream>>>(x, emb, wih_b, bih_b, bhh_b,
                                     fc1w, fc1b, fc2w, fc2b, hf16, out);
}

// Round 11
// 2121.034 us; speedup vs baseline: 1.1606x; 1.1468x over previous
//
#include <hip/hip_runtime.h>

typedef unsigned int  u32;
typedef unsigned short u16;
typedef unsigned long long u64;
typedef _Float16 half8 __attribute__((ext_vector_type(8)));
typedef short   short8 __attribute__((ext_vector_type(8)));
typedef float   f32x4  __attribute__((ext_vector_type(4)));

#define T_LEN 512
#define BATCH 64
#define EDIM  256
#define HDIM  256
#define G4    1024   // 4*H gate rows

// ---------- numeric helpers ----------
static __device__ __forceinline__ u16 f2bf(float f) {
  u32 u = __builtin_bit_cast(u32, f);
  u = (u + 0x7fffu + ((u >> 16) & 1u)) >> 16;   // RTNE
  return (u16)u;
}
static __device__ __forceinline__ u16 f2h(float a) {
  _Float16 ha = (_Float16)a;
  return __builtin_bit_cast(u16, ha);
}
static __device__ __forceinline__ float h2f(u16 a) {
  return (float)__builtin_bit_cast(_Float16, a);
}
// v_rcp-based: avoids the ~9-instr IEEE div sequence (bench has no fast-math)
static __device__ __forceinline__ float sigf(float x) {
  return __builtin_amdgcn_rcpf(1.0f + __expf(-x));
}
static __device__ __forceinline__ float tanhfast(float x) {
  return fmaf(2.0f, __builtin_amdgcn_rcpf(1.0f + __expf(-2.0f * x)), -1.0f);
}

// ---------- kernel 1: pack W_hh_f into f16 MFMA A-frag order -----------------
// Wf[mt][kt][lane][ji]: flat ((mt*8+kt)*64+lane)*8+ji; value =
// W[mt*16+(lane&15)][kt*32+(lane>>4)*8+ji].
// Also pack kt6-7 frags contiguously per row-block j for imm-offset streaming:
// Wst[(j*8 + (kt-6)*4 + q)*64 + l][8]  (per-lane base + {0..7}*1024 B).
__global__ __launch_bounds__(256) void k_prep(const float* __restrict__ whh,
                                              u16* __restrict__ Wf,
                                              u16* __restrict__ Wst) {
  int cell = blockIdx.x * 256 + threadIdx.x;  // 32768 cells, 8 f16 each
  int mt = cell >> 9, kt = (cell >> 6) & 7, l = cell & 63;
  int gr = mt * 16 + (l & 15);
  int c0 = kt * 32 + (l >> 4) * 8;
  const float4* src = (const float4*)(whh + (size_t)gr * 256 + c0);
  float4 a = src[0], b = src[1];
  u16 o[8] = { f2h(a.x), f2h(a.y), f2h(a.z), f2h(a.w),
               f2h(b.x), f2h(b.y), f2h(b.z), f2h(b.w) };
  *(uint4*)(Wf + (size_t)cell * 8) = *(uint4*)o;
  if (kt >= 6) {
    int q = mt >> 4, jj = mt & 15, s = (kt - 6) * 4 + q;
    *(uint4*)(Wst + ((size_t)(jj * 8 + s) * 64 + l) * 8) = *(uint4*)o;
  }
}

// ---------- kernel 2: xproj via bf16 MFMA, f16 out in k_rnn D-frag order -----
// xp2[t][bg][mt'][lane][r] with mt' = j16*4 + q  (q=gate, j16=row-block).
// (IDENTICAL to the proven round-0 version.)
#define LDSPITCH 264
__global__ __launch_bounds__(256) void k_xproj(const int* __restrict__ x,
                                               const float* __restrict__ emb,
                                               const float* __restrict__ wih,
                                               const float* __restrict__ bih,
                                               const float* __restrict__ bhh,
                                               u16* __restrict__ xp2) {
  __shared__ u16 smA[64 * LDSPITCH];
  __shared__ u16 smB[64 * LDSPITCH];
  const int tn = blockIdx.x, t = blockIdx.y;
  const int tid = threadIdx.x;
  const int r = tid >> 2, q4 = tid & 3;

  { // stage A: emb rows (batch r, timestep t), fp32 -> bf16
    int eidx = x[r * T_LEN + t];
    const float4* src = (const float4*)(emb + (size_t)eidx * EDIM + q4 * 64);
    u16* dst = smA + r * LDSPITCH + q4 * 64;
    #pragma unroll
    for (int i = 0; i < 16; ++i) {
      float4 v = src[i];
      uint2 p;
      p.x = (u32)f2bf(v.x) | ((u32)f2bf(v.y) << 16);
      p.y = (u32)f2bf(v.z) | ((u32)f2bf(v.w) << 16);
      *(uint2*)&dst[i * 4] = p;
    }
  }
  { // stage B: w_ih rows g = tn*64 + r
    const float4* src = (const float4*)(wih + (size_t)(tn * 64 + r) * EDIM + q4 * 64);
    u16* dst = smB + r * LDSPITCH + q4 * 64;
    #pragma unroll
    for (int i = 0; i < 16; ++i) {
      float4 v = src[i];
      uint2 p;
      p.x = (u32)f2bf(v.x) | ((u32)f2bf(v.y) << 16);
      p.y = (u32)f2bf(v.z) | ((u32)f2bf(v.w) << 16);
      *(uint2*)&dst[i * 4] = p;
    }
  }
  __syncthreads();

  const int wv = tid >> 6, lane = tid & 63;
  const int lm = lane & 15, q = lane >> 4;
  f32x4 acc[4];
  #pragma unroll
  for (int nt = 0; nt < 4; ++nt) acc[nt] = (f32x4){0.f, 0.f, 0.f, 0.f};

  const u16* pa = smA + (wv * 16 + lm) * LDSPITCH + q * 8;
  const u16* pb = smB + lm * LDSPITCH + q * 8;
  #pragma unroll
  for (int ks = 0; ks < 8; ++ks) {
    short8 av = *(const short8*)(pa + ks * 32);
    #pragma unroll
    for (int nt = 0; nt < 4; ++nt) {
      short8 bv = *(const short8*)(pb + nt * 16 * LDSPITCH + ks * 32);
      acc[nt] = __builtin_amdgcn_mfma_f32_16x16x32_bf16(av, bv, acc[nt], 0, 0, 0);
    }
  }
  // D: row = batch = wv*16+q*4+rr, col = gate row g = tn*64+nt*16+lm.
  #pragma unroll
  for (int nt = 0; nt < 4; ++nt) {
    int g = tn * 64 + nt * 16 + lm;
    float bias = bih[g] + bhh[g];
    int gq = g >> 8, j16 = (g >> 4) & 15, qdd = (g & 15) >> 2, rb = g & 3;
    int mtp = j16 * 4 + gq;
    #pragma unroll
    for (int rr = 0; rr < 4; ++rr) {
      int bl = q * 4 + rr;   // batch-in-group; bg = wv
      size_t idx = ((((size_t)t * 4 + wv) * 64 + mtp) * 64 + (qdd * 16 + bl)) * 4 + rb;
      xp2[idx] = f2h(acc[nt][rr] + bias);
    }
  }
}

// ---------- kernel 3: recurrence, 4 WGs x 1024 thr, single in-CU barrier -----
// WG bg owns batches [bg*16,+16).  16 waves; wave v owns row-block j = v,
// all 4 gates q; 4 h-elements per lane per step.
// Weights: kt0-1 pinned in AGPRs ("+a", 32 regs) and kt2-3 pinned in arch
// VGPRs ("+v", 32 regs) -- SPLIT PIN.  r7 (16 frags "+v") filled the arch
// class and shuttled the working set through AGPRs (~220 phantom VALU/step);
// r8-r10 (16 frags "+a") filled the AGPR class and spilled the working set
// to scratch (WRITE 576-1088 KB).  With 32 AGPR demand the allocator can set
// accum_offset ~96: arch 96 >= 32 (weights) + ~55 (working set) -> neither.
// kt4-5 LDS (128 KB wave-private); kt6-7 streamed from Wst (imm offsets).
// S6/S7 liveness windows enforced by sched_barrier(0); acc C-INITIALIZED
// from xp (z-add folded into MFMA); xv prefetched at step top, converted
// into acc after the gates (acc regs reused).  Final iteration peeled.
// Gate nonlinearities via v_rcp.  Raw `lgkmcnt(0); s_barrier` once per step.
__global__ __launch_bounds__(1024, 4) void k_rnn(const u16* __restrict__ Wf,
                                                 const u16* __restrict__ Wst,
                                                 const u16* __restrict__ xp2,
                                                 u16* __restrict__ hf) {
  extern __shared__ u16 sm[];
  u16* smW = sm;               // 16 waves x 8 frags x 512 u16 = 65536 u16 (128 KB)
  u16* smH = sm + 65536;       // 2 x 4224 u16 (pitch 264) = 16.5 KB
  const int bg = blockIdx.x;
  const int tid = threadIdx.x;
  const int v = tid >> 6, l = tid & 63;
  const int j = v;                    // row-block 0..15
  const int bl = l & 15, qd = l >> 4;

  // ---- kt0-3 resident in RF: kt0-1 -> AGPR, kt2-3 -> arch VGPR ----
  half8 Wr[4][4];
  #pragma unroll
  for (int q = 0; q < 4; ++q)
    #pragma unroll
    for (int kt = 0; kt < 4; ++kt)
      Wr[q][kt] = *(const half8*)(Wf + ((size_t)((q * 16 + j) * 8 + kt) * 64 + l) * 8);
  #pragma unroll
  for (int q = 0; q < 4; ++q) {
    asm volatile("" : "+a"(Wr[q][0]), "+a"(Wr[q][1]));   // 8 frags -> 32 AGPR
    asm volatile("" : "+v"(Wr[q][2]), "+v"(Wr[q][3]));   // 8 frags -> 32 arch
  }

  // ---- kt4-5 staged to LDS (wave-private slots; no cross-wave deps) ----
  #pragma unroll
  for (int q = 0; q < 4; ++q)
    #pragma unroll
    for (int ki = 0; ki < 2; ++ki) {
      uint4 tv = *(const uint4*)(Wf + ((size_t)((q * 16 + j) * 8 + 4 + ki) * 64 + l) * 8);
      *(uint4*)(smW + ((size_t)(v * 8 + q * 2 + ki) * 512 + l * 8)) = tv;
    }

  { // zero h dbuf: 2 x 4224 u16 = 4224 u32
    u32* hz = (u32*)smH;
    for (int i = tid; i < 4224; i += 1024) hz[i] = 0;
  }
  __syncthreads();

  float c[4] = {0.f, 0.f, 0.f, 0.f};

  const u16* xbase = xp2 + (size_t)bg * 16384 + (size_t)j * 1024 + l * 4;  // += 65536/t
  const u16* hrd0 = smH + bl * 264 + qd * 8;
  const int  hwof = bl * 264 + j * 16 + qd * 4;
  const u16* wst_l = Wst + (size_t)j * 4096 + l * 8;   // 8 frags at +s*512 u16

  // prologue: C-init acc for t=0 from xp[0]
  f32x4 acc[4];
  {
    uint2 x0[4];
    #pragma unroll
    for (int q = 0; q < 4; ++q)
      x0[q] = *(const uint2*)(xbase + q * 256);
    #pragma unroll
    for (int q = 0; q < 4; ++q)
      acc[q] = (f32x4){ h2f((u16)x0[q].x), h2f((u16)(x0[q].x >> 16)),
                        h2f((u16)x0[q].y), h2f((u16)(x0[q].y >> 16)) };
  }

#define STEP(PAR) do {                                                         \
    u32 zoff = 0;                                                              \
    asm volatile("" : "+v"(zoff));   /* block LICM on the kt6-7 re-stream */   \
    const u16* wp = wst_l + zoff;                                              \
    uint4 S6[4];                                                               \
    _Pragma("unroll")                                                          \
    for (int q = 0; q < 4; ++q) S6[q] = *(const uint4*)(wp + q * 512);         \
    uint2 xv[4];                     /* next step's xp: consumed at C-init */  \
    _Pragma("unroll")                                                          \
    for (int q = 0; q < 4; ++q)                                                \
      xv[q] = *(const uint2*)(xbase + 65536 + q * 256);                        \
    const u16* hb = hrd0 + (PAR) * 4224;                                       \
    _Pragma("unroll")                                                          \
    for (int kt = 0; kt < 4; ++kt) {                /* kt0-3: RF weights */    \
      half8 Bf = *(const half8*)(hb + kt * 32);                                \
      _Pragma("unroll")                                                        \
      for (int q = 0; q < 4; ++q)                                              \
        acc[q] = __builtin_amdgcn_mfma_f32_16x16x32_f16(Wr[q][kt], Bf,         \
                                                        acc[q], 0, 0, 0);      \
    }                                                                          \
    _Pragma("unroll")                                                          \
    for (int kt = 4; kt < 6; ++kt) {                /* kt4-5: LDS weights */   \
      half8 Bf = *(const half8*)(hb + kt * 32);                                \
      _Pragma("unroll")                                                        \
      for (int q = 0; q < 4; ++q) {                                            \
        half8 Af = *(const half8*)(smW +                                       \
                     ((size_t)(v * 8 + q * 2 + (kt - 4)) * 512 + l * 8));      \
        acc[q] = __builtin_amdgcn_mfma_f32_16x16x32_f16(Af, Bf,                \
                                                        acc[q], 0, 0, 0);      \
      }                                                                        \
    }                                                                          \
    __builtin_amdgcn_sched_barrier(0);              /* S6 consumed NOW */      \
    {                                                                          \
      half8 Bf = *(const half8*)(hb + 6 * 32);      /* kt6: S6 dies here */    \
      _Pragma("unroll")                                                        \
      for (int q = 0; q < 4; ++q)                                              \
        acc[q] = __builtin_amdgcn_mfma_f32_16x16x32_f16(                       \
            __builtin_bit_cast(half8, S6[q]), Bf, acc[q], 0, 0, 0);            \
    }                                                                          \
    __builtin_amdgcn_sched_barrier(0);              /* S7 cannot hoist */      \
    uint4 S7[4];                                                               \
    _Pragma("unroll")                                                          \
    for (int q = 0; q < 4; ++q)                                                \
      S7[q] = *(const uint4*)(wp + 2048 + q * 512);                            \
    {                                                                          \
      half8 Bf = *(const half8*)(hb + 7 * 32);      /* kt7: S7 */              \
      _Pragma("unroll")                                                        \
      for (int q = 0; q < 4; ++q)                                              \
        acc[q] = __builtin_amdgcn_mfma_f32_16x16x32_f16(                       \
            __builtin_bit_cast(half8, S7[q]), Bf, acc[q], 0, 0, 0);            \
    }                                                                          \
    float hn[4];                     /* gates: z = acc directly (C-init) */    \
    _Pragma("unroll")                                                          \
    for (int r = 0; r < 4; ++r) {                                              \
      float zi = acc[0][r], zf = acc[1][r], zg = acc[2][r], zo = acc[3][r];    \
      c[r] = sigf(zf) * c[r] + sigf(zi) * tanhfast(zg);                        \
      hn[r] = sigf(zo) * tanhfast(c[r]);                                       \
    }                                                                          \
    u32 lo = __builtin_bit_cast(u32, __builtin_amdgcn_cvt_pkrtz(hn[0], hn[1]));\
    u32 hi = __builtin_bit_cast(u32, __builtin_amdgcn_cvt_pkrtz(hn[2], hn[3]));\
    *(uint2*)(smH + (1 - (PAR)) * 4224 + hwof) = make_uint2(lo, hi);           \
    _Pragma("unroll")                /* C-init next acc (regs reused) */       \
    for (int q = 0; q < 4; ++q)                                                \
      acc[q] = (f32x4){ h2f((u16)xv[q].x), h2f((u16)(xv[q].x >> 16)),          \
                        h2f((u16)xv[q].y), h2f((u16)(xv[q].y >> 16)) };        \
    xbase += 65536;                                                            \
    asm volatile("s_waitcnt lgkmcnt(0)\n\ts_barrier" ::: "memory");            \
    __builtin_amdgcn_sched_barrier(0);              /* rule #18 fence */       \
  } while (0)

  for (int tt = 0; tt < 255; ++tt) {   // steps 0..509
    STEP(0);
    STEP(1);
  }
  STEP(0);                             // step 510 (C-inits acc from xp[511])

  { // final step t=511: no prefetch, no smH write, output to hf, no barrier
    u32 zoff = 0;
    asm volatile("" : "+v"(zoff));
    const u16* wp = wst_l + zoff;
    uint4 S6[4];
    #pragma unroll
    for (int q = 0; q < 4; ++q) S6[q] = *(const uint4*)(wp + q * 512);
    const u16* hb = hrd0 + 4224;       // parity 1
    #pragma unroll
    for (int kt = 0; kt < 4; ++kt) {
      half8 Bf = *(const half8*)(hb + kt * 32);
      #pragma unroll
      for (int q = 0; q < 4; ++q)
        acc[q] = __builtin_amdgcn_mfma_f32_16x16x32_f16(Wr[q][kt], Bf, acc[q], 0, 0, 0);
    }
    #pragma unroll
    for (int kt = 4; kt < 6; ++kt) {
      half8 Bf = *(const half8*)(hb + kt * 32);
      #pragma unroll
      for (int q = 0; q < 4; ++q) {
        half8 Af = *(const half8*)(smW + ((size_t)(v * 8 + q * 2 + (kt - 4)) * 512 + l * 8));
        acc[q] = __builtin_amdgcn_mfma_f32_16x16x32_f16(Af, Bf, acc[q], 0, 0, 0);
      }
    }
    {
      half8 Bf = *(const half8*)(hb + 6 * 32);
      #pragma unroll
      for (int q = 0; q < 4; ++q)
        acc[q] = __builtin_amdgcn_mfma_f32_16x16x32_f16(
            __builtin_bit_cast(half8, S6[q]), Bf, acc[q], 0, 0, 0);
    }
    uint4 S7[4];
    #pragma unroll
    for (int q = 0; q < 4; ++q)
      S7[q] = *(const uint4*)(wp + 2048 + q * 512);
    {
      half8 Bf = *(const half8*)(hb + 7 * 32);
      #pragma unroll
      for (int q = 0; q < 4; ++q)
        acc[q] = __builtin_amdgcn_mfma_f32_16x16x32_f16(
            __builtin_bit_cast(half8, S7[q]), Bf, acc[q], 0, 0, 0);
    }
    float hn[4];
    #pragma unroll
    for (int r = 0; r < 4; ++r) {
      float zi = acc[0][r], zf = acc[1][r], zg = acc[2][r], zo = acc[3][r];
      c[r] = sigf(zf) * c[r] + sigf(zi) * tanhfast(zg);
      hn[r] = sigf(zo) * tanhfast(c[r]);
    }
    u32 lo = __builtin_bit_cast(u32, __builtin_amdgcn_cvt_pkrtz(hn[0], hn[1]));
    u32 hi = __builtin_bit_cast(u32, __builtin_amdgcn_cvt_pkrtz(hn[2], hn[3]));
    *(uint2*)(hf + (size_t)(bg * 16 + bl) * 256 + j * 16 + qd * 4) = make_uint2(lo, hi);
  }
#undef STEP
}

// ---------- kernel 4: backward single step + fc1 + fc2 ----------
__global__ __launch_bounds__(256) void k_tail(const int* __restrict__ x,
                                              const float* __restrict__ emb,
                                              const float* __restrict__ wihb,
                                              const float* __restrict__ bihb,
                                              const float* __restrict__ bhhb,
                                              const float* __restrict__ fc1w,
                                              const float* __restrict__ fc1b,
                                              const float* __restrict__ fc2w,
                                              const float* __restrict__ fc2b,
                                              const u16* __restrict__ hf,
                                              float* __restrict__ out) {
  const int b = blockIdx.x, tid = threadIdx.x;
  __shared__ float e[EDIM], hb[HDIM], hfl[HDIM], f1[24];
  e[tid]   = emb[(size_t)x[b * T_LEN + (T_LEN - 1)] * EDIM + tid];
  hfl[tid] = h2f(hf[b * HDIM + tid]);
  __syncthreads();

  float z[4];
  #pragma unroll
  for (int gq = 0; gq < 4; ++gq) {
    int g = gq * HDIM + tid;
    float s = bihb[g] + bhhb[g];
    const float4* wr = (const float4*)(wihb + (size_t)g * EDIM);
    #pragma unroll 8
    for (int k = 0; k < 64; ++k) {
      float4 w = wr[k];
      s += w.x * e[4 * k] + w.y * e[4 * k + 1] + w.z * e[4 * k + 2] + w.w * e[4 * k + 3];
    }
    z[gq] = s;
  }
  float cb = sigf(z[0]) * tanhfast(z[2]);   // c0 = 0
  hb[tid] = sigf(z[3]) * tanhfast(cb);
  __syncthreads();

  if (tid < 24) {
    float s = fc1b[tid];
    const float* w = fc1w + tid * 512;
    #pragma unroll 8
    for (int k = 0; k < HDIM; ++k) s += w[k] * hfl[k] + w[HDIM + k] * hb[k];
    f1[tid] = fmaxf(s, 0.f);
  }
  __syncthreads();
  if (tid < 2) {
    float s = fc2b[tid];
    #pragma unroll
    for (int k = 0; k < 24; ++k) s += fc2w[tid * 24 + k] * f1[k];
    out[b * 2 + tid] = s;
  }
}

// ---------- launch ----------
extern "C" void kernel_launch(void* const* d_in, const int* in_sizes, int n_in,
                              void* d_out, int out_size, void* d_ws, size_t ws_size,
                              hipStream_t stream) {
  const int*   x     = (const int*)  d_in[0];
  const float* emb   = (const float*)d_in[1];
  const float* wih_f = (const float*)d_in[2];
  const float* whh_f = (const float*)d_in[3];
  const float* bih_f = (const float*)d_in[4];
  const float* bhh_f = (const float*)d_in[5];
  const float* wih_b = (const float*)d_in[6];
  // d_in[7] = w_hh_b: unused (backward runs exactly one step from zero state)
  const float* bih_b = (const float*)d_in[8];
  const float* bhh_b = (const float*)d_in[9];
  const float* fc1w  = (const float*)d_in[10];
  const float* fc1b  = (const float*)d_in[11];
  const float* fc2w  = (const float*)d_in[12];
  const float* fc2b  = (const float*)d_in[13];
  float* out = (float*)d_out;

  // workspace: xp2 64 MiB | Wf 512 KiB | Wst 128 KiB | hf16 32 KiB
  char* ws = (char*)d_ws;
  u16* xp2  = (u16*)ws;
  u16* Wf   = (u16*)(ws + 67108864);
  u16* Wst  = (u16*)(ws + 67108864 + 524288);
  u16* hf16 = (u16*)(ws + 67108864 + 524288 + 131072);

  k_prep <<<128, 256, 0, stream>>>(whh_f, Wf, Wst);
  k_xproj<<<dim3(16, 512), 256, 0, stream>>>(x, emb, wih_f, bih_f, bhh_f, xp2);
  k_rnn  <<<4, 1024, 147968, stream>>>(Wf, Wst, xp2, hf16);
  k_tail <<<BATCH, 256, 0, stream>>>(x, emb, wih_b, bih_b, bhh_b,
                                     fc1w, fc1b, fc2w, fc2b, hf16, out);
}

// Round 12
// 1491.000 us; speedup vs baseline: 1.6511x; 1.4226x over previous
//
#include <hip/hip_runtime.h>

typedef unsigned int  u32;
typedef unsigned short u16;
typedef unsigned long long u64;
typedef _Float16 half8 __attribute__((ext_vector_type(8)));
typedef short   short8 __attribute__((ext_vector_type(8)));
typedef float   f32x4  __attribute__((ext_vector_type(4)));

#define T_LEN 512
#define BATCH 64
#define EDIM  256
#define HDIM  256
#define G4    1024   // 4*H gate rows

// ---------- numeric helpers ----------
static __device__ __forceinline__ u16 f2bf(float f) {
  u32 u = __builtin_bit_cast(u32, f);
  u = (u + 0x7fffu + ((u >> 16) & 1u)) >> 16;   // RTNE
  return (u16)u;
}
static __device__ __forceinline__ u16 f2h(float a) {
  _Float16 ha = (_Float16)a;
  return __builtin_bit_cast(u16, ha);
}
static __device__ __forceinline__ float h2f(u16 a) {
  return (float)__builtin_bit_cast(_Float16, a);
}
// v_rcp-based: avoids the ~9-instr IEEE div sequence (bench has no fast-math)
static __device__ __forceinline__ float sigf(float x) {
  return __builtin_amdgcn_rcpf(1.0f + __expf(-x));
}
static __device__ __forceinline__ float tanhfast(float x) {
  return fmaf(2.0f, __builtin_amdgcn_rcpf(1.0f + __expf(-2.0f * x)), -1.0f);
}

// ---------- kernel 1: pack W_hh_f into f16 MFMA A-frag order -----------------
// Wf[mt][kt][lane][ji]: flat ((mt*8+kt)*64+lane)*8+ji; value =
// W[mt*16+(lane&15)][kt*32+(lane>>4)*8+ji].
// Also pack kt6-7 frags contiguously per row-block j for imm-offset streaming:
// Wst[(j*8 + (kt-6)*4 + q)*64 + l][8]  (per-lane base + {0..7}*1024 B).
__global__ __launch_bounds__(256) void k_prep(const float* __restrict__ whh,
                                              u16* __restrict__ Wf,
                                              u16* __restrict__ Wst) {
  int cell = blockIdx.x * 256 + threadIdx.x;  // 32768 cells, 8 f16 each
  int mt = cell >> 9, kt = (cell >> 6) & 7, l = cell & 63;
  int gr = mt * 16 + (l & 15);
  int c0 = kt * 32 + (l >> 4) * 8;
  const float4* src = (const float4*)(whh + (size_t)gr * 256 + c0);
  float4 a = src[0], b = src[1];
  u16 o[8] = { f2h(a.x), f2h(a.y), f2h(a.z), f2h(a.w),
               f2h(b.x), f2h(b.y), f2h(b.z), f2h(b.w) };
  *(uint4*)(Wf + (size_t)cell * 8) = *(uint4*)o;
  if (kt >= 6) {
    int q = mt >> 4, jj = mt & 15, s = (kt - 6) * 4 + q;
    *(uint4*)(Wst + ((size_t)(jj * 8 + s) * 64 + l) * 8) = *(uint4*)o;
  }
}

// ---------- kernel 2: xproj via bf16 MFMA, f16 out in k_rnn D-frag order -----
// xp2[t][bg][mt'][lane][r] with mt' = j16*4 + q  (q=gate, j16=row-block).
// (IDENTICAL to the proven round-0 version.)
#define LDSPITCH 264
__global__ __launch_bounds__(256) void k_xproj(const int* __restrict__ x,
                                               const float* __restrict__ emb,
                                               const float* __restrict__ wih,
                                               const float* __restrict__ bih,
                                               const float* __restrict__ bhh,
                                               u16* __restrict__ xp2) {
  __shared__ u16 smA[64 * LDSPITCH];
  __shared__ u16 smB[64 * LDSPITCH];
  const int tn = blockIdx.x, t = blockIdx.y;
  const int tid = threadIdx.x;
  const int r = tid >> 2, q4 = tid & 3;

  { // stage A: emb rows (batch r, timestep t), fp32 -> bf16
    int eidx = x[r * T_LEN + t];
    const float4* src = (const float4*)(emb + (size_t)eidx * EDIM + q4 * 64);
    u16* dst = smA + r * LDSPITCH + q4 * 64;
    #pragma unroll
    for (int i = 0; i < 16; ++i) {
      float4 v = src[i];
      uint2 p;
      p.x = (u32)f2bf(v.x) | ((u32)f2bf(v.y) << 16);
      p.y = (u32)f2bf(v.z) | ((u32)f2bf(v.w) << 16);
      *(uint2*)&dst[i * 4] = p;
    }
  }
  { // stage B: w_ih rows g = tn*64 + r
    const float4* src = (const float4*)(wih + (size_t)(tn * 64 + r) * EDIM + q4 * 64);
    u16* dst = smB + r * LDSPITCH + q4 * 64;
    #pragma unroll
    for (int i = 0; i < 16; ++i) {
      float4 v = src[i];
      uint2 p;
      p.x = (u32)f2bf(v.x) | ((u32)f2bf(v.y) << 16);
      p.y = (u32)f2bf(v.z) | ((u32)f2bf(v.w) << 16);
      *(uint2*)&dst[i * 4] = p;
    }
  }
  __syncthreads();

  const int wv = tid >> 6, lane = tid & 63;
  const int lm = lane & 15, q = lane >> 4;
  f32x4 acc[4];
  #pragma unroll
  for (int nt = 0; nt < 4; ++nt) acc[nt] = (f32x4){0.f, 0.f, 0.f, 0.f};

  const u16* pa = smA + (wv * 16 + lm) * LDSPITCH + q * 8;
  const u16* pb = smB + lm * LDSPITCH + q * 8;
  #pragma unroll
  for (int ks = 0; ks < 8; ++ks) {
    short8 av = *(const short8*)(pa + ks * 32);
    #pragma unroll
    for (int nt = 0; nt < 4; ++nt) {
      short8 bv = *(const short8*)(pb + nt * 16 * LDSPITCH + ks * 32);
      acc[nt] = __builtin_amdgcn_mfma_f32_16x16x32_bf16(av, bv, acc[nt], 0, 0, 0);
    }
  }
  // D: row = batch = wv*16+q*4+rr, col = gate row g = tn*64+nt*16+lm.
  #pragma unroll
  for (int nt = 0; nt < 4; ++nt) {
    int g = tn * 64 + nt * 16 + lm;
    float bias = bih[g] + bhh[g];
    int gq = g >> 8, j16 = (g >> 4) & 15, qdd = (g & 15) >> 2, rb = g & 3;
    int mtp = j16 * 4 + gq;
    #pragma unroll
    for (int rr = 0; rr < 4; ++rr) {
      int bl = q * 4 + rr;   // batch-in-group; bg = wv
      size_t idx = ((((size_t)t * 4 + wv) * 64 + mtp) * 64 + (qdd * 16 + bl)) * 4 + rb;
      xp2[idx] = f2h(acc[nt][rr] + bias);
    }
  }
}

// ---------- kernel 3: recurrence, 4 WGs x 1024 thr, single in-CU barrier -----
// WG bg owns batches [bg*16,+16).  16 waves; wave v owns row-block j = v,
// all 4 gates q; 4 h-elements per lane per step.
// Weights: kt0-3 RF (16 frags, "+v" pinned -- the ONLY non-spilling config:
// r8-r11 showed any "+a" placement spills the working set to scratch, while
// all-"+v" overflows into the AGPR file via fast v_accvgpr moves); kt4-5 LDS
// (128 KB, wave-private); kt6-7 streamed from Wst (imm offsets, laundered).
// acc C-INITIALIZED from the xp fragment (z-add folded into MFMA, free).
// xp prefetched one step ahead in a register double buffer.
// Gate nonlinearities via v_rcp.  Raw `lgkmcnt(0); s_barrier` once per step.
__global__ __launch_bounds__(1024, 4) void k_rnn(const u16* __restrict__ Wf,
                                                 const u16* __restrict__ Wst,
                                                 const u16* __restrict__ xp2,
                                                 u16* __restrict__ hf) {
  extern __shared__ u16 sm[];
  u16* smW = sm;               // 16 waves x 8 frags x 512 u16 = 65536 u16 (128 KB)
  u16* smH = sm + 65536;       // 2 x 4224 u16 (pitch 264) = 16.5 KB
  const int bg = blockIdx.x;
  const int tid = threadIdx.x;
  const int v = tid >> 6, l = tid & 63;
  const int j = v;                    // row-block 0..15
  const int bl = l & 15, qd = l >> 4;

  // ---- kt0-3 resident in RF ----
  half8 Wr[4][4];
  #pragma unroll
  for (int q = 0; q < 4; ++q)
    #pragma unroll
    for (int kt = 0; kt < 4; ++kt)
      Wr[q][kt] = *(const half8*)(Wf + ((size_t)((q * 16 + j) * 8 + kt) * 64 + l) * 8);
  #pragma unroll
  for (int q = 0; q < 4; ++q)
    asm volatile("" : "+v"(Wr[q][0]), "+v"(Wr[q][1]), "+v"(Wr[q][2]), "+v"(Wr[q][3]));

  // ---- kt4-5 staged to LDS (wave-private slots; no cross-wave deps) ----
  #pragma unroll
  for (int q = 0; q < 4; ++q)
    #pragma unroll
    for (int ki = 0; ki < 2; ++ki) {
      uint4 tv = *(const uint4*)(Wf + ((size_t)((q * 16 + j) * 8 + 4 + ki) * 64 + l) * 8);
      *(uint4*)(smW + ((size_t)(v * 8 + q * 2 + ki) * 512 + l * 8)) = tv;
    }

  { // zero h dbuf: 2 x 4224 u16 = 4224 u32
    u32* hz = (u32*)smH;
    for (int i = tid; i < 4224; i += 1024) hz[i] = 0;
  }
  __syncthreads();

  float c[4] = {0.f, 0.f, 0.f, 0.f};

  const u16* xbase = xp2 + (size_t)bg * 16384 + (size_t)j * 1024 + l * 4;  // += 65536/t
  const u16* hrd0 = smH + bl * 264 + qd * 8;
  const int  hwof = bl * 264 + j * 16 + qd * 4;
  const u16* wst_l = Wst + (size_t)j * 4096 + l * 8;   // 8 frags at +s*512 u16

  // prologue: xp for t=0 into buffer A
  uint2 xA[4], xB[4];
  #pragma unroll
  for (int q = 0; q < 4; ++q)
    xA[q] = *(const uint2*)(xbase + q * 256);

#define STEP(T, XC, XN) do {                                                   \
    u32 zoff = 0;                                                              \
    asm volatile("" : "+v"(zoff));   /* block LICM on the kt6-7 re-stream */   \
    const u16* wp = wst_l + zoff;                                              \
    uint4 S6[4];                                                               \
    _Pragma("unroll")                                                          \
    for (int q = 0; q < 4; ++q)                                                \
      S6[q] = *(const uint4*)(wp + q * 512);                                   \
    _Pragma("unroll")                /* prefetch next step's xp */             \
    for (int q = 0; q < 4; ++q)                                                \
      XN[q] = *(const uint2*)(xbase + 65536 + q * 256);                        \
    const u16* hb = hrd0 + ((T) & 1) * 4224;                                   \
    f32x4 acc[4];                    /* C-init from xp: z-add is free */       \
    _Pragma("unroll")                                                          \
    for (int q = 0; q < 4; ++q)                                                \
      acc[q] = (f32x4){ h2f((u16)XC[q].x), h2f((u16)(XC[q].x >> 16)),          \
                        h2f((u16)XC[q].y), h2f((u16)(XC[q].y >> 16)) };        \
    _Pragma("unroll")                                                          \
    for (int kt = 0; kt < 4; ++kt) {                /* kt0-3: RF weights */    \
      half8 Bf = *(const half8*)(hb + kt * 32);                                \
      _Pragma("unroll")                                                        \
      for (int q = 0; q < 4; ++q)                                              \
        acc[q] = __builtin_amdgcn_mfma_f32_16x16x32_f16(Wr[q][kt], Bf,         \
                                                        acc[q], 0, 0, 0);      \
    }                                                                          \
    _Pragma("unroll")                                                          \
    for (int kt = 4; kt < 6; ++kt) {                /* kt4-5: LDS weights */   \
      half8 Bf = *(const half8*)(hb + kt * 32);                                \
      _Pragma("unroll")                                                        \
      for (int q = 0; q < 4; ++q) {                                            \
        half8 Af = *(const half8*)(smW +                                       \
                     ((size_t)(v * 8 + q * 2 + (kt - 4)) * 512 + l * 8));      \
        acc[q] = __builtin_amdgcn_mfma_f32_16x16x32_f16(Af, Bf,                \
                                                        acc[q], 0, 0, 0);      \
      }                                                                        \
    }                                                                          \
    {                                                                          \
      half8 Bf = *(const half8*)(hb + 6 * 32);      /* kt6: S6 (dies here) */  \
      _Pragma("unroll")                                                        \
      for (int q = 0; q < 4; ++q)                                              \
        acc[q] = __builtin_amdgcn_mfma_f32_16x16x32_f16(                       \
            __builtin_bit_cast(half8, S6[q]), Bf, acc[q], 0, 0, 0);            \
    }                                                                          \
    uint4 S7[4];                     /* S7 after kt6 */                        \
    _Pragma("unroll")                                                          \
    for (int q = 0; q < 4; ++q)                                                \
      S7[q] = *(const uint4*)(wp + 2048 + q * 512);                            \
    {                                                                          \
      half8 Bf = *(const half8*)(hb + 7 * 32);      /* kt7: S7 */              \
      _Pragma("unroll")                                                        \
      for (int q = 0; q < 4; ++q)                                              \
        acc[q] = __builtin_amdgcn_mfma_f32_16x16x32_f16(                       \
            __builtin_bit_cast(half8, S7[q]), Bf, acc[q], 0, 0, 0);            \
    }                                                                          \
    float hn[4];                     /* gates: z = acc directly (C-init) */    \
    _Pragma("unroll")                                                          \
    for (int r = 0; r < 4; ++r) {                                              \
      float zi = acc[0][r], zf = acc[1][r], zg = acc[2][r], zo = acc[3][r];    \
      c[r] = sigf(zf) * c[r] + sigf(zi) * tanhfast(zg);                        \
      hn[r] = sigf(zo) * tanhfast(c[r]);                                       \
    }                                                                          \
    u32 lo = __builtin_bit_cast(u32, __builtin_amdgcn_cvt_pkrtz(hn[0], hn[1]));\
    u32 hi = __builtin_bit_cast(u32, __builtin_amdgcn_cvt_pkrtz(hn[2], hn[3]));\
    if ((T) == T_LEN - 1) {                                                    \
      *(uint2*)(hf + (size_t)(bg * 16 + bl) * 256 + j * 16 + qd * 4) =         \
          make_uint2(lo, hi);                                                  \
    } else {                                                                   \
      *(uint2*)(smH + (((T) + 1) & 1) * 4224 + hwof) = make_uint2(lo, hi);     \
    }                                                                          \
    xbase += 65536;                                                            \
    asm volatile("s_waitcnt lgkmcnt(0)\n\ts_barrier" ::: "memory");            \
  } while (0)

  for (int tt = 0; tt < T_LEN; tt += 2) {
    STEP(tt, xA, xB);
    STEP(tt + 1, xB, xA);
  }
#undef STEP
}

// ---------- kernel 4: backward single step + fc1 + fc2 ----------
__global__ __launch_bounds__(256) void k_tail(const int* __restrict__ x,
                                              const float* __restrict__ emb,
                                              const float* __restrict__ wihb,
                                              const float* __restrict__ bihb,
                                              const float* __restrict__ bhhb,
                                              const float* __restrict__ fc1w,
                                              const float* __restrict__ fc1b,
                                              const float* __restrict__ fc2w,
                                              const float* __restrict__ fc2b,
                                              const u16* __restrict__ hf,
                                              float* __restrict__ out) {
  const int b = blockIdx.x, tid = threadIdx.x;
  __shared__ float e[EDIM], hb[HDIM], hfl[HDIM], f1[24];
  e[tid]   = emb[(size_t)x[b * T_LEN + (T_LEN - 1)] * EDIM + tid];
  hfl[tid] = h2f(hf[b * HDIM + tid]);
  __syncthreads();

  float z[4];
  #pragma unroll
  for (int gq = 0; gq < 4; ++gq) {
    int g = gq * HDIM + tid;
    float s = bihb[g] + bhhb[g];
    const float4* wr = (const float4*)(wihb + (size_t)g * EDIM);
    #pragma unroll 8
    for (int k = 0; k < 64; ++k) {
      float4 w = wr[k];
      s += w.x * e[4 * k] + w.y * e[4 * k + 1] + w.z * e[4 * k + 2] + w.w * e[4 * k + 3];
    }
    z[gq] = s;
  }
  float cb = sigf(z[0]) * tanhfast(z[2]);   // c0 = 0
  hb[tid] = sigf(z[3]) * tanhfast(cb);
  __syncthreads();

  if (tid < 24) {
    float s = fc1b[tid];
    const float* w = fc1w + tid * 512;
    #pragma unroll 8
    for (int k = 0; k < HDIM; ++k) s += w[k] * hfl[k] + w[HDIM + k] * hb[k];
    f1[tid] = fmaxf(s, 0.f);
  }
  __syncthreads();
  if (tid < 2) {
    float s = fc2b[tid];
    #pragma unroll
    for (int k = 0; k < 24; ++k) s += fc2w[tid * 24 + k] * f1[k];
    out[b * 2 + tid] = s;
  }
}

// ---------- launch ----------
extern "C" void kernel_launch(void* const* d_in, const int* in_sizes, int n_in,
                              void* d_out, int out_size, void* d_ws, size_t ws_size,
                              hipStream_t stream) {
  const int*   x     = (const int*)  d_in[0];
  const float* emb   = (const float*)d_in[1];
  const float* wih_f = (const float*)d_in[2];
  const float* whh_f = (const float*)d_in[3];
  const float* bih_f = (const float*)d_in[4];
  const float* bhh_f = (const float*)d_in[5];
  const float* wih_b = (const float*)d_in[6];
  // d_in[7] = w_hh_b: unused (backward runs exactly one step from zero state)
  const float* bih_b = (const float*)d_in[8];
  const float* bhh_b = (const float*)d_in[9];
  const float* fc1w  = (const float*)d_in[10];
  const float* fc1b  = (const float*)d_in[11];
  const float* fc2w  = (const float*)d_in[12];
  const float* fc2b  = (const float*)d_in[13];
  float* out = (float*)d_out;

  // workspace: xp2 64 MiB | Wf 512 KiB | Wst 128 KiB | hf16 32 KiB
  char* ws = (char*)d_ws;
  u16* xp2  = (u16*)ws;
  u16* Wf   = (u16*)(ws + 67108864);
  u16* Wst  = (u16*)(ws + 67108864 + 524288);
  u16* hf16 = (u16*)(ws + 67108864 + 524288 + 131072);

  k_prep <<<128, 256, 0, stream>>>(whh_f, Wf, Wst);
  k_xproj<<<dim3(16, 512), 256, 0, stream>>>(x, emb, wih_f, bih_f, bhh_f, xp2);
  k_rnn  <<<4, 1024, 147968, stream>>>(Wf, Wst, xp2, hf16);
  k_tail <<<BATCH, 256, 0, stream>>>(x, emb, wih_b, bih_b, bhh_b,
                                     fc1w, fc1b, fc2w, fc2b, hf16, out);
}